// Round 1
// baseline (1112.747 us; speedup 1.0000x reference)
//
#include <hip/hip_runtime.h>
#include <hip/hip_bf16.h>
#include <cstdint>
#include <cstddef>

// LRU forward: B=16, T=4096, IN=OUT=N=512
// Pipeline: prep weights (bf16) -> convert u (bf16) -> GEMM1 (Bu) -> chunked
// complex scan (carry/prefix/apply) -> GEMM2 (y).
// d_out doubles as scratch for Bu (bf16 interleaved re/im) before y overwrites it.

using short8 = __attribute__((ext_vector_type(8))) short;
using short4v = __attribute__((ext_vector_type(4))) short;
using f32x4 = __attribute__((ext_vector_type(4))) float;

#define BDIM 16
#define TDIM 4096
#define MTOT (BDIM * TDIM)   // 65536
#define CHUNK 64
#define NCHUNK (TDIM / CHUNK) // 64

__device__ __forceinline__ unsigned short f2bf(float f) {
    unsigned u = __float_as_uint(f);
    u = u + 0x7FFFu + ((u >> 16) & 1u);   // RNE
    return (unsigned short)(u >> 16);
}
__device__ __forceinline__ float bflo(unsigned w) { return __uint_as_float(w << 16); }
__device__ __forceinline__ float bfhi(unsigned w) { return __uint_as_float(w & 0xFFFF0000u); }

// ---------------- weight prep ----------------
__global__ void prep_w1(const float* __restrict__ B_re, const float* __restrict__ B_im,
                        const float* __restrict__ gamma_log, unsigned short* __restrict__ W1) {
    int i = blockIdx.x * 256 + threadIdx.x;  // 0..511
    int n = blockIdx.y;                      // 0..1023
    float v;
    if (n < 512) v = B_re[n * 512 + i] * expf(gamma_log[n]);
    else         v = B_im[(n - 512) * 512 + i] * expf(gamma_log[n - 512]);
    W1[(size_t)n * 512 + i] = f2bf(v);
}

__global__ void prep_w2(const float* __restrict__ C_re, const float* __restrict__ C_im,
                        const float* __restrict__ D, unsigned short* __restrict__ W2) {
    int k = blockIdx.x * 256 + threadIdx.x;  // 0..1535
    int o = blockIdx.y;                      // 0..511
    float v;
    if (k < 1024) {
        int n = k >> 1;
        v = (k & 1) ? -2.0f * C_im[o * 512 + n] : 2.0f * C_re[o * 512 + n];
    } else {
        v = D[o * 512 + (k - 1024)];
    }
    W2[(size_t)o * 1536 + k] = f2bf(v);
}

// ---------------- u -> bf16 into packed A (cols 1024..1535) ----------------
__global__ void convert_u(const float4* __restrict__ u4, unsigned short* __restrict__ Apack) {
    size_t idx = (size_t)blockIdx.x * 256 + threadIdx.x;  // < 65536*128
    float4 v = u4[idx];
    size_t row = idx >> 7;
    int c4 = (int)(idx & 127);
    unsigned lo = (unsigned)f2bf(v.x) | ((unsigned)f2bf(v.y) << 16);
    unsigned hi = (unsigned)f2bf(v.z) | ((unsigned)f2bf(v.w) << 16);
    uint2* dst = reinterpret_cast<uint2*>(Apack + row * 1536 + 1024 + c4 * 4);
    *dst = make_uint2(lo, hi);
}

// ---------------- MFMA GEMM (NT): C[m][n] = sum_k A[m][k]*B[n][k] ----------------
// 128x128 tile, BK=64, 4 waves (2x2 of 64x64), reg-staged LDS with XOR swizzle.
// OUT_MODE 0: f32 to C (ldc=512). OUT_MODE 1: bf16 interleaved (re cols<512 -> ushort 2n,
// im cols>=512 -> ushort 2n+1) into rows of 1024 ushort.
template <int OUT_MODE>
__global__ __launch_bounds__(256) void gemm_nt(const unsigned short* __restrict__ A, int lda,
                                               const unsigned short* __restrict__ Bm, int ldb,
                                               void* __restrict__ Cout, int K) {
    __shared__ unsigned short As[128 * 64];
    __shared__ unsigned short Bs[128 * 64];
    const int tid = threadIdx.x;
    const int bn = blockIdx.x, bm = blockIdx.y;
    const int lane = tid & 63, w = tid >> 6;
    const int wm = (w >> 1) * 64, wn = (w & 1) * 64;
    const int ml = lane & 15, g = lane >> 4;

    f32x4 acc[4][4] = {};

    const int srow = tid >> 3;  // 0..31
    const int scol = tid & 7;   // 16B chunk within 128B row
    const size_t abase = (size_t)(bm * 128) * lda;
    const size_t bbase = (size_t)(bn * 128) * ldb;

    const int ktiles = K >> 6;
    for (int kt = 0; kt < ktiles; ++kt) {
        uint4 ar[4], br[4];
#pragma unroll
        for (int p = 0; p < 4; ++p) {
            int row = p * 32 + srow;
            ar[p] = *reinterpret_cast<const uint4*>(A + abase + (size_t)row * lda + kt * 64 + scol * 8);
            br[p] = *reinterpret_cast<const uint4*>(Bm + bbase + (size_t)row * ldb + kt * 64 + scol * 8);
        }
        __syncthreads();  // previous compute done before LDS overwrite
#pragma unroll
        for (int p = 0; p < 4; ++p) {
            int row = p * 32 + srow;
            int off = row * 128 + ((scol * 16) ^ ((row & 7) << 4));
            *reinterpret_cast<uint4*>(reinterpret_cast<char*>(As) + off) = ar[p];
            *reinterpret_cast<uint4*>(reinterpret_cast<char*>(Bs) + off) = br[p];
        }
        __syncthreads();
#pragma unroll
        for (int kk = 0; kk < 2; ++kk) {
            short8 af[4], bfr[4];
#pragma unroll
            for (int mt = 0; mt < 4; ++mt) {
                int row = wm + mt * 16 + ml;
                int sw = (row & 7) << 4;
                int kb0 = kk * 64 + g * 8;
                short4v lo = *reinterpret_cast<const short4v*>(
                    reinterpret_cast<char*>(As) + row * 128 + (kb0 ^ sw));
                short4v hi = *reinterpret_cast<const short4v*>(
                    reinterpret_cast<char*>(As) + row * 128 + ((kb0 + 32) ^ sw));
                af[mt] = __builtin_shufflevector(lo, hi, 0, 1, 2, 3, 4, 5, 6, 7);
            }
#pragma unroll
            for (int nt = 0; nt < 4; ++nt) {
                int row = wn + nt * 16 + ml;
                int sw = (row & 7) << 4;
                int kb0 = kk * 64 + g * 8;
                short4v lo = *reinterpret_cast<const short4v*>(
                    reinterpret_cast<char*>(Bs) + row * 128 + (kb0 ^ sw));
                short4v hi = *reinterpret_cast<const short4v*>(
                    reinterpret_cast<char*>(Bs) + row * 128 + ((kb0 + 32) ^ sw));
                bfr[nt] = __builtin_shufflevector(lo, hi, 0, 1, 2, 3, 4, 5, 6, 7);
            }
#pragma unroll
            for (int mt = 0; mt < 4; ++mt)
#pragma unroll
                for (int nt = 0; nt < 4; ++nt)
                    acc[mt][nt] = __builtin_amdgcn_mfma_f32_16x16x32_bf16(af[mt], bfr[nt], acc[mt][nt], 0, 0, 0);
        }
    }

#pragma unroll
    for (int mt = 0; mt < 4; ++mt) {
#pragma unroll
        for (int nt = 0; nt < 4; ++nt) {
#pragma unroll
            for (int r = 0; r < 4; ++r) {
                int grow = bm * 128 + wm + mt * 16 + g * 4 + r;
                int gcol = bn * 128 + wn + nt * 16 + ml;
                float v = acc[mt][nt][r];
                if (OUT_MODE == 0) {
                    reinterpret_cast<float*>(Cout)[(size_t)grow * 512 + gcol] = v;
                } else {
                    int ci = (gcol < 512) ? (gcol * 2) : ((gcol - 512) * 2 + 1);
                    reinterpret_cast<unsigned short*>(Cout)[(size_t)grow * 1024 + ci] = f2bf(v);
                }
            }
        }
    }
}

// ---------------- scan ----------------
__global__ void scan_carry(const unsigned* __restrict__ Bu, const float* __restrict__ nu_log,
                           const float* __restrict__ theta_log, float2* __restrict__ carry) {
    int q = blockIdx.x * 256 + threadIdx.x;  // < 16*64*512
    int n = q & 511, c = (q >> 9) & 63, b = q >> 15;
    float mod = expf(-expf(nu_log[n]));
    float th = expf(theta_log[n]);
    float s, co;
    sincosf(th, &s, &co);
    float Lre = mod * co, Lim = mod * s;
    const unsigned* p = Bu + ((size_t)(b * TDIM + c * CHUNK)) * 512 + n;
    float xr = 0.f, xi = 0.f;
#pragma unroll 8
    for (int t = 0; t < CHUNK; ++t) {
        unsigned wv = p[(size_t)t * 512];
        float nr = fmaf(Lre, xr, fmaf(-Lim, xi, bflo(wv)));
        float ni = fmaf(Lre, xi, fmaf(Lim, xr, bfhi(wv)));
        xr = nr; xi = ni;
    }
    carry[(size_t)(b * NCHUNK + c) * 512 + n] = make_float2(xr, xi);
}

__global__ void scan_prefix(const float2* __restrict__ carry, const float* __restrict__ nu_log,
                            const float* __restrict__ theta_log, float2* __restrict__ prefix) {
    int q = blockIdx.x * 256 + threadIdx.x;  // < 8192
    int n = q & 511, b = q >> 9;
    float e = expf(nu_log[n]);
    float modL = expf(-(float)CHUNK * e);
    float th = expf(theta_log[n]);
    double ang = fmod((double)CHUNK * (double)th, 6.283185307179586);
    float s, co;
    sincosf((float)ang, &s, &co);
    float Lre = modL * co, Lim = modL * s;
    float pr = 0.f, pi = 0.f;
    for (int c = 0; c < NCHUNK; ++c) {
        size_t idx = (size_t)(b * NCHUNK + c) * 512 + n;
        prefix[idx] = make_float2(pr, pi);
        float2 ev = carry[idx];
        float nr = fmaf(Lre, pr, fmaf(-Lim, pi, ev.x));
        float ni = fmaf(Lre, pi, fmaf(Lim, pr, ev.y));
        pr = nr; pi = ni;
    }
}

__global__ void scan_apply(const unsigned* __restrict__ Bu, const float* __restrict__ nu_log,
                           const float* __restrict__ theta_log, const float2* __restrict__ prefix,
                           unsigned* __restrict__ Apack32) {
    int q = blockIdx.x * 256 + threadIdx.x;
    int n = q & 511, c = (q >> 9) & 63, b = q >> 15;
    float mod = expf(-expf(nu_log[n]));
    float th = expf(theta_log[n]);
    float s, co;
    sincosf(th, &s, &co);
    float Lre = mod * co, Lim = mod * s;
    const unsigned* p = Bu + ((size_t)(b * TDIM + c * CHUNK)) * 512 + n;
    unsigned* xo = Apack32 + ((size_t)(b * TDIM + c * CHUNK)) * 768 + n;  // row = 1536 bf16 = 768 words
    float2 pv = prefix[(size_t)(b * NCHUNK + c) * 512 + n];
    float xr = pv.x, xi = pv.y;
#pragma unroll 8
    for (int t = 0; t < CHUNK; ++t) {
        unsigned wv = p[(size_t)t * 512];
        float nr = fmaf(Lre, xr, fmaf(-Lim, xi, bflo(wv)));
        float ni = fmaf(Lre, xi, fmaf(Lim, xr, bfhi(wv)));
        xr = nr; xi = ni;
        xo[(size_t)t * 768] = (unsigned)f2bf(xr) | ((unsigned)f2bf(xi) << 16);
    }
}

extern "C" void kernel_launch(void* const* d_in, const int* in_sizes, int n_in,
                              void* d_out, int out_size, void* d_ws, size_t ws_size,
                              hipStream_t stream) {
    const float* u         = (const float*)d_in[0];
    const float* nu_log    = (const float*)d_in[1];
    const float* theta_log = (const float*)d_in[2];
    const float* gamma_log = (const float*)d_in[3];
    const float* B_re      = (const float*)d_in[4];
    const float* B_im      = (const float*)d_in[5];
    const float* C_re      = (const float*)d_in[6];
    const float* C_im      = (const float*)d_in[7];
    const float* D         = (const float*)d_in[8];

    char* ws = (char*)d_ws;
    unsigned short* Apack = (unsigned short*)ws;                    // 65536*1536*2 = 201326592 B
    size_t off = (size_t)MTOT * 1536 * 2;
    unsigned short* W1 = (unsigned short*)(ws + off); off += 1024 * 512 * 2;   // 1 MB
    unsigned short* W2 = (unsigned short*)(ws + off); off += 512 * 1536 * 2;   // 1.5 MB
    float2* carry  = (float2*)(ws + off); off += (size_t)BDIM * NCHUNK * 512 * 8;  // 4 MB
    float2* prefix = (float2*)(ws + off); off += (size_t)BDIM * NCHUNK * 512 * 8;  // 4 MB
    // total ws usage ~203 MB

    unsigned short* Bu = (unsigned short*)d_out;  // 65536*1024 ushort == out bytes exactly

    prep_w1<<<dim3(2, 1024), 256, 0, stream>>>(B_re, B_im, gamma_log, W1);
    prep_w2<<<dim3(6, 512), 256, 0, stream>>>(C_re, C_im, D, W2);
    convert_u<<<32768, 256, 0, stream>>>((const float4*)u, Apack);
    // GEMM1: Bu[m][n(re/im interleaved)] = u_bf16 . W1^T  (M=65536,N=1024,K=512)
    gemm_nt<1><<<dim3(8, 512), 256, 0, stream>>>(Apack + 1024, 1536, W1, 512, (void*)Bu, 512);
    scan_carry<<<2048, 256, 0, stream>>>((const unsigned*)Bu, nu_log, theta_log, carry);
    scan_prefix<<<32, 256, 0, stream>>>(carry, nu_log, theta_log, prefix);
    scan_apply<<<2048, 256, 0, stream>>>((const unsigned*)Bu, nu_log, theta_log, prefix, (unsigned*)Apack);
    // GEMM2: y = Apack . W2^T  (M=65536,N=512,K=1536), f32 out
    gemm_nt<0><<<dim3(4, 512), 256, 0, stream>>>(Apack, 1536, W2, 1536, d_out, 1536);
}

// Round 2
// 365.524 us; speedup vs baseline: 3.0442x; 3.0442x over previous
//
#include <hip/hip_runtime.h>
#include <hip/hip_bf16.h>
#include <cstdint>
#include <cstddef>

// LRU forward: B=16, T=4096, IN=OUT=N=512
// prep weights (bf16, fragment-permuted+swizzled layout) -> convert u ->
// GEMM1 (Bu, m97-style global_load_lds MFMA) -> chunked scan -> GEMM2 (y).
// d_out doubles as scratch for Bu before y overwrites it.
//
// Stored layout for all GEMM operands ("perm layout"): row-major rows, each
// 64-k tile is 128 bytes arranged as 8 chunks of 16B. Chunk c at row r holds
// fragment chunk cc = c ^ (r&7) (XOR bank swizzle), where fragment chunk
// cc = kk*4+g holds k = {kk*32+g*4+j, kk*32+16+g*4+j} (j=0..3), i.e. one
// ds_read_b128 = one MFMA operand fragment, conflict-free.

using short8 = __attribute__((ext_vector_type(8))) short;
using f32x4 = __attribute__((ext_vector_type(4))) float;

#define BDIM 16
#define TDIM 4096
#define MTOT (BDIM * TDIM)   // 65536
#define CHUNK 64
#define NCHUNK (TDIM / CHUNK) // 64

__device__ __forceinline__ unsigned short f2bf(float f) {
    unsigned u = __float_as_uint(f);
    u = u + 0x7FFFu + ((u >> 16) & 1u);   // RNE
    return (unsigned short)(u >> 16);
}
__device__ __forceinline__ float bflo(unsigned w) { return __uint_as_float(w << 16); }
__device__ __forceinline__ float bfhi(unsigned w) { return __uint_as_float(w & 0xFFFF0000u); }

// byte offset of element (row, kt tile, kp in [0,64)) in perm layout
__device__ __forceinline__ size_t perm_off(int row, int kt, int kp, int rowbytes) {
    int kk = kp >> 5, km = kp & 31;
    int half = km >> 4;
    int g = (km & 15) >> 2, j = km & 3;
    int cc = (kk << 2) | g;
    int c = cc ^ (row & 7);
    return (size_t)row * rowbytes + kt * 128 + (c << 4) + half * 8 + j * 2;
}

__device__ __forceinline__ void gload_lds16(const void* g, void* l) {
    __builtin_amdgcn_global_load_lds((const __attribute__((address_space(1))) void*)g,
                                     (__attribute__((address_space(3))) void*)l, 16, 0, 0);
}

// ---------------- weight prep ----------------
// W1 rows interleaved: row 2n = gamma[n]*B_re[n,:], row 2n+1 = gamma[n]*B_im[n,:]
__global__ void prep_w1(const float* __restrict__ B_re, const float* __restrict__ B_im,
                        const float* __restrict__ gamma_log, char* __restrict__ W1) {
    int i = blockIdx.x * 256 + threadIdx.x;  // 0..511 (k)
    int r = blockIdx.y;                      // 0..1023 (row)
    int n = r >> 1;
    float gmm = expf(gamma_log[n]);
    float v = (r & 1) ? B_im[n * 512 + i] * gmm : B_re[n * 512 + i] * gmm;
    *(unsigned short*)(W1 + perm_off(r, i >> 6, i & 63, 1024)) = f2bf(v);
}

// W2 row o, k<1024: even k -> 2*C_re[o][k/2], odd -> -2*C_im[o][k/2]; k>=1024 -> D
__global__ void prep_w2(const float* __restrict__ C_re, const float* __restrict__ C_im,
                        const float* __restrict__ D, char* __restrict__ W2) {
    int k = blockIdx.x * 256 + threadIdx.x;  // 0..1535
    int o = blockIdx.y;                      // 0..511
    float v;
    if (k < 1024) {
        int n = k >> 1;
        v = (k & 1) ? -2.0f * C_im[o * 512 + n] : 2.0f * C_re[o * 512 + n];
    } else {
        v = D[o * 512 + (k - 1024)];
    }
    *(unsigned short*)(W2 + perm_off(o, k >> 6, k & 63, 3072)) = f2bf(v);
}

// ---------------- u -> bf16 into perm-layout Apack (k = 1024..1535) ----------------
__global__ void convert_u(const float4* __restrict__ u4, char* __restrict__ Apack) {
    size_t idx = (size_t)blockIdx.x * 256 + threadIdx.x;  // < 65536*128
    float4 v = u4[idx];
    int row = (int)(idx >> 7);
    int c4 = (int)(idx & 127);
    int kg = 1024 + c4 * 4;
    unsigned lo = (unsigned)f2bf(v.x) | ((unsigned)f2bf(v.y) << 16);
    unsigned hi = (unsigned)f2bf(v.z) | ((unsigned)f2bf(v.w) << 16);
    // 4 consecutive k share (kk,g,half), j=0..3 -> one aligned 8B store
    size_t off = perm_off(row, kg >> 6, kg & 63, 3072);
    *reinterpret_cast<uint2*>(Apack + off) = make_uint2(lo, hi);
}

// ---------------- MFMA GEMM (NT, perm layout): C[m][n] = sum_k A[m][k]*B[n][k] ----
// 128x128 tile, BK=64, 4 waves (2x2 of 64x64). global_load_lds(16B) staging,
// linear LDS (swizzle baked into global layout), single ds_read_b128 per fragment.
template <int OUT_MODE, int NBN>
__global__ __launch_bounds__(256) void gemm_nt(const char* __restrict__ A, int ldab,
                                               const char* __restrict__ Bm, int ldbb,
                                               void* __restrict__ Cout, int ktiles) {
    __shared__ __align__(16) char As[128 * 128];
    __shared__ __align__(16) char Bs[128 * 128];
    const int tid = threadIdx.x;
    const int lane = tid & 63, w = tid >> 6;
    // bijective XCD swizzle; bm-major per XCD for A-panel L2 reuse
    const int bid = blockIdx.x;
    const int cpx = gridDim.x >> 3;
    const int swz = (bid & 7) * cpx + (bid >> 3);
    const int bm = swz / NBN, bn = swz % NBN;
    const int wm = (w >> 1) * 64, wn = (w & 1) * 64;
    const int ml = lane & 15, g = lane >> 4;

    const int srow = w * 32 + (lane >> 3);   // + p*8
    const int schunk = lane & 7;
    const char* Ag = A + (size_t)(bm * 128 + srow) * ldab + schunk * 16;
    const char* Bg = Bm + (size_t)(bn * 128 + srow) * ldbb + schunk * 16;
    char* AsW = &As[w * 4096];
    char* BsW = &Bs[w * 4096];

    f32x4 acc[4][4] = {};

    for (int kt = 0; kt < ktiles; ++kt) {
#pragma unroll
        for (int p = 0; p < 4; ++p) {
            gload_lds16(Ag + (size_t)p * 8 * ldab + kt * 128, AsW + p * 1024);
            gload_lds16(Bg + (size_t)p * 8 * ldbb + kt * 128, BsW + p * 1024);
        }
        __syncthreads();   // drains vmcnt: tile staged
#pragma unroll
        for (int kk = 0; kk < 2; ++kk) {
            short8 af[4], bfr[4];
#pragma unroll
            for (int mt = 0; mt < 4; ++mt) {
                int r = wm + mt * 16 + ml;
                af[mt] = *reinterpret_cast<const short8*>(
                    As + r * 128 + ((((kk << 2) | g) ^ (r & 7)) << 4));
            }
#pragma unroll
            for (int nt = 0; nt < 4; ++nt) {
                int r = wn + nt * 16 + ml;
                bfr[nt] = *reinterpret_cast<const short8*>(
                    Bs + r * 128 + ((((kk << 2) | g) ^ (r & 7)) << 4));
            }
#pragma unroll
            for (int mt = 0; mt < 4; ++mt)
#pragma unroll
                for (int nt = 0; nt < 4; ++nt)
                    acc[mt][nt] = __builtin_amdgcn_mfma_f32_16x16x32_bf16(af[mt], bfr[nt], acc[mt][nt], 0, 0, 0);
        }
        __syncthreads();   // all reads done before next overwrite
    }

#pragma unroll
    for (int mt = 0; mt < 4; ++mt) {
#pragma unroll
        for (int nt = 0; nt < 4; ++nt) {
#pragma unroll
            for (int r = 0; r < 4; ++r) {
                int grow = bm * 128 + wm + mt * 16 + g * 4 + r;
                int gcol = bn * 128 + wn + nt * 16 + ml;
                float v = acc[mt][nt][r];
                if (OUT_MODE == 0) {
                    reinterpret_cast<float*>(Cout)[(size_t)grow * 512 + gcol] = v;
                } else {
                    // W1 rows already interleaved: gcol == packed (re,im) index
                    reinterpret_cast<unsigned short*>(Cout)[(size_t)grow * 1024 + gcol] = f2bf(v);
                }
            }
        }
    }
}

// ---------------- scan ----------------
__global__ void scan_carry(const unsigned* __restrict__ Bu, const float* __restrict__ nu_log,
                           const float* __restrict__ theta_log, float2* __restrict__ carry) {
    int q = blockIdx.x * 256 + threadIdx.x;  // < 16*64*512
    int n = q & 511, c = (q >> 9) & 63, b = q >> 15;
    float mod = expf(-expf(nu_log[n]));
    float th = expf(theta_log[n]);
    float s, co;
    sincosf(th, &s, &co);
    float Lre = mod * co, Lim = mod * s;
    const unsigned* p = Bu + ((size_t)(b * TDIM + c * CHUNK)) * 512 + n;
    float xr = 0.f, xi = 0.f;
#pragma unroll 8
    for (int t = 0; t < CHUNK; ++t) {
        unsigned wv = p[(size_t)t * 512];
        float nr = fmaf(Lre, xr, fmaf(-Lim, xi, bflo(wv)));
        float ni = fmaf(Lre, xi, fmaf(Lim, xr, bfhi(wv)));
        xr = nr; xi = ni;
    }
    carry[(size_t)(b * NCHUNK + c) * 512 + n] = make_float2(xr, xi);
}

__global__ void scan_prefix(const float2* __restrict__ carry, const float* __restrict__ nu_log,
                            const float* __restrict__ theta_log, float2* __restrict__ prefix) {
    int q = blockIdx.x * 256 + threadIdx.x;  // < 8192
    int n = q & 511, b = q >> 9;
    float e = expf(nu_log[n]);
    float modL = expf(-(float)CHUNK * e);
    float th = expf(theta_log[n]);
    double ang = fmod((double)CHUNK * (double)th, 6.283185307179586);
    float s, co;
    sincosf((float)ang, &s, &co);
    float Lre = modL * co, Lim = modL * s;
    float pr = 0.f, pi = 0.f;
    for (int c = 0; c < NCHUNK; ++c) {
        size_t idx = (size_t)(b * NCHUNK + c) * 512 + n;
        prefix[idx] = make_float2(pr, pi);
        float2 ev = carry[idx];
        float nr = fmaf(Lre, pr, fmaf(-Lim, pi, ev.x));
        float ni = fmaf(Lre, pi, fmaf(Lim, pr, ev.y));
        pr = nr; pi = ni;
    }
}

__global__ void scan_apply(const unsigned* __restrict__ Bu, const float* __restrict__ nu_log,
                           const float* __restrict__ theta_log, const float2* __restrict__ prefix,
                           char* __restrict__ Apack) {
    int q = blockIdx.x * 256 + threadIdx.x;
    int n = q & 511, c = (q >> 9) & 63, b = q >> 15;
    float mod = expf(-expf(nu_log[n]));
    float th = expf(theta_log[n]);
    float s, co;
    sincosf(th, &s, &co);
    float Lre = mod * co, Lim = mod * s;
    const unsigned* p = Bu + ((size_t)(b * TDIM + c * CHUNK)) * 512 + n;
    float2 pv = prefix[(size_t)(b * NCHUNK + c) * 512 + n];
    float xr = pv.x, xi = pv.y;
    // x pair (2n, 2n+1): per-thread constant parts of perm offset
    int kp = (2 * n) & 63;
    int kk = kp >> 5, km = kp & 31;
    int half = km >> 4, gg = (km & 15) >> 2, j = km & 3;
    int cc = (kk << 2) | gg;
    int partial = (n >> 5) * 128 + half * 8 + j * 2;  // kt*128 + within-chunk
    int row0 = b * TDIM + c * CHUNK;
#pragma unroll 8
    for (int t = 0; t < CHUNK; ++t) {
        unsigned wv = p[(size_t)t * 512];
        float nr = fmaf(Lre, xr, fmaf(-Lim, xi, bflo(wv)));
        float ni = fmaf(Lre, xi, fmaf(Lim, xr, bfhi(wv)));
        xr = nr; xi = ni;
        int row = row0 + t;
        size_t off = (size_t)row * 3072 + ((cc ^ (row & 7)) << 4) + partial;
        *reinterpret_cast<unsigned*>(Apack + off) =
            (unsigned)f2bf(xr) | ((unsigned)f2bf(xi) << 16);
    }
}

extern "C" void kernel_launch(void* const* d_in, const int* in_sizes, int n_in,
                              void* d_out, int out_size, void* d_ws, size_t ws_size,
                              hipStream_t stream) {
    const float* u         = (const float*)d_in[0];
    const float* nu_log    = (const float*)d_in[1];
    const float* theta_log = (const float*)d_in[2];
    const float* gamma_log = (const float*)d_in[3];
    const float* B_re      = (const float*)d_in[4];
    const float* B_im      = (const float*)d_in[5];
    const float* C_re      = (const float*)d_in[6];
    const float* C_im      = (const float*)d_in[7];
    const float* D         = (const float*)d_in[8];

    char* ws = (char*)d_ws;
    char* Apack = ws;                                   // 65536*3072 B = 201 MB (perm layout)
    size_t off = (size_t)MTOT * 3072;
    char* W1 = ws + off; off += 1024 * 1024;            // 1 MB
    char* W2 = ws + off; off += 512 * 3072;             // 1.5 MB
    float2* carry  = (float2*)(ws + off); off += (size_t)BDIM * NCHUNK * 512 * 8;
    float2* prefix = (float2*)(ws + off); off += (size_t)BDIM * NCHUNK * 512 * 8;

    unsigned short* Bu = (unsigned short*)d_out;  // 65536*1024 ushort == out bytes

    prep_w1<<<dim3(2, 1024), 256, 0, stream>>>(B_re, B_im, gamma_log, W1);
    prep_w2<<<dim3(6, 512), 256, 0, stream>>>(C_re, C_im, D, W2);
    convert_u<<<32768, 256, 0, stream>>>((const float4*)u, Apack);
    // GEMM1: Bu = u_bf16 . W1^T  (M=65536, N=1024, K=512); A = u-part of Apack
    gemm_nt<1, 8><<<4096, 256, 0, stream>>>(Apack + 16 * 128, 3072, W1, 1024, (void*)Bu, 8);
    scan_carry<<<2048, 256, 0, stream>>>((const unsigned*)Bu, nu_log, theta_log, carry);
    scan_prefix<<<32, 256, 0, stream>>>(carry, nu_log, theta_log, prefix);
    scan_apply<<<2048, 256, 0, stream>>>((const unsigned*)Bu, nu_log, theta_log, prefix, Apack);
    // GEMM2: y = Apack . W2^T  (M=65536, N=512, K=1536), f32 out
    gemm_nt<0, 4><<<2048, 256, 0, stream>>>(Apack, 3072, W2, 3072, d_out, 24);
}

// Round 3
// 320.196 us; speedup vs baseline: 3.4752x; 1.1416x over previous
//
#include <hip/hip_runtime.h>
#include <hip/hip_bf16.h>
#include <cstdint>
#include <cstddef>

// LRU forward: B=16, T=4096, IN=OUT=N=512
// prep weights (bf16, perm layout) -> convert u -> GEMM1 (Bu, 256^2 counted-vmcnt
// pipeline, carry fused in epilogue) -> prefix -> apply -> GEMM2 (y).
// d_out doubles as scratch for Bu before y overwrites it.
//
// Perm layout: row-major rows; each 64-k tile is 128 B = 8 chunks of 16 B.
// Chunk c at row r holds fragment chunk cc = c ^ (r&7) (XOR bank swizzle);
// fragment chunk cc = kk*4+g holds k = {kk*32+g*4+j, kk*32+16+g*4+j}, so one
// ds_read_b128 = one MFMA operand fragment, conflict-free, and global_load_lds
// staging is plain contiguous 16B chunks (LDS linear).

using short8 = __attribute__((ext_vector_type(8))) short;
using f32x4 = __attribute__((ext_vector_type(4))) float;

#define BDIM 16
#define TDIM 4096
#define MTOT (BDIM * TDIM)   // 65536
#define CHUNK 64
#define NCHUNK (TDIM / CHUNK) // 64

__device__ __forceinline__ unsigned short f2bf(float f) {
    unsigned u = __float_as_uint(f);
    u = u + 0x7FFFu + ((u >> 16) & 1u);   // RNE
    return (unsigned short)(u >> 16);
}
__device__ __forceinline__ float bflo(unsigned w) { return __uint_as_float(w << 16); }
__device__ __forceinline__ float bfhi(unsigned w) { return __uint_as_float(w & 0xFFFF0000u); }

__device__ __forceinline__ size_t perm_off(int row, int kt, int kp, int rowbytes) {
    int kk = kp >> 5, km = kp & 31;
    int half = km >> 4;
    int g = (km & 15) >> 2, j = km & 3;
    int cc = (kk << 2) | g;
    int c = cc ^ (row & 7);
    return (size_t)row * rowbytes + kt * 128 + (c << 4) + half * 8 + j * 2;
}

__device__ __forceinline__ void gload_lds16(const void* g, void* l) {
    __builtin_amdgcn_global_load_lds((const __attribute__((address_space(1))) void*)g,
                                     (__attribute__((address_space(3))) void*)l, 16, 0, 0);
}

// ---------------- weight prep ----------------
__global__ void prep_w1(const float* __restrict__ B_re, const float* __restrict__ B_im,
                        const float* __restrict__ gamma_log, char* __restrict__ W1) {
    int i = blockIdx.x * 256 + threadIdx.x;  // 0..511 (k)
    int r = blockIdx.y;                      // 0..1023 (row)
    int n = r >> 1;
    float gmm = expf(gamma_log[n]);
    float v = (r & 1) ? B_im[n * 512 + i] * gmm : B_re[n * 512 + i] * gmm;
    *(unsigned short*)(W1 + perm_off(r, i >> 6, i & 63, 1024)) = f2bf(v);
}

__global__ void prep_w2(const float* __restrict__ C_re, const float* __restrict__ C_im,
                        const float* __restrict__ D, char* __restrict__ W2) {
    int k = blockIdx.x * 256 + threadIdx.x;  // 0..1535
    int o = blockIdx.y;                      // 0..511
    float v;
    if (k < 1024) {
        int n = k >> 1;
        v = (k & 1) ? -2.0f * C_im[o * 512 + n] : 2.0f * C_re[o * 512 + n];
    } else {
        v = D[o * 512 + (k - 1024)];
    }
    *(unsigned short*)(W2 + perm_off(o, k >> 6, k & 63, 3072)) = f2bf(v);
}

__global__ void convert_u(const float4* __restrict__ u4, char* __restrict__ Apack) {
    size_t idx = (size_t)blockIdx.x * 256 + threadIdx.x;  // < 65536*128
    float4 v = u4[idx];
    int row = (int)(idx >> 7);
    int c4 = (int)(idx & 127);
    int kg = 1024 + c4 * 4;
    unsigned lo = (unsigned)f2bf(v.x) | ((unsigned)f2bf(v.y) << 16);
    unsigned hi = (unsigned)f2bf(v.z) | ((unsigned)f2bf(v.w) << 16);
    size_t off = perm_off(row, kg >> 6, kg & 63, 3072);
    *reinterpret_cast<uint2*>(Apack + off) = make_uint2(lo, hi);
}

// ---------------- 256x256 pipelined MFMA GEMM (NT, perm layout) ----------------
// 8 waves (2M x 4N), BK=64, double-buffered 128 KB LDS, counted vmcnt, setprio.
// OUT_MODE 0: f32 C (ld 512). OUT_MODE 1: bf16 Bu (ld 1024) + fused chunk-carry.
#define ASM_VMCNT8 asm volatile("s_waitcnt vmcnt(8)" ::: "memory")
#define ASM_VMCNT0 asm volatile("s_waitcnt vmcnt(0)" ::: "memory")
#define ASM_LGKM0  asm volatile("s_waitcnt lgkmcnt(0)" ::: "memory")

template <int OUT_MODE, int NBN>
__global__ __launch_bounds__(512, 2) void gemm_nt(const char* __restrict__ A, int ldab,
                                                  const char* __restrict__ Bm, int ldbb,
                                                  void* __restrict__ Cout, int ktiles,
                                                  float2* __restrict__ carry,
                                                  const float* __restrict__ nu_log,
                                                  const float* __restrict__ theta_log) {
    __shared__ __align__(16) char lds[131072];  // A0|B0|A1|B1 of 32 KB each
    const int tid = threadIdx.x;
    const int lane = tid & 63, w = tid >> 6;
    const int bid = blockIdx.x;
    const int cpx = gridDim.x >> 3;             // grid divisible by 8
    const int swz = (bid & 7) * cpx + (bid >> 3);
    const int bm = swz / NBN, bn = swz % NBN;
    const int wm = (w >> 2) * 128, wn = (w & 3) * 64;
    const int ml = lane & 15, g = lane >> 4;

    const char* Agr = A + (size_t)(bm * 256 + w * 32 + (lane >> 3)) * ldab + (lane & 7) * 16;
    const char* Bgr = Bm + (size_t)(bn * 256 + w * 32 + (lane & 63 ? (lane >> 3) : 0)) * ldbb + (lane & 7) * 16;
    // (lane>>3) is correct for all lanes; the ?: above is identity for lane!=0 and lane==0 -> keep simple:
    // recompute cleanly:
    const char* Bgr2 = Bm + (size_t)(bn * 256 + w * 32 + (lane >> 3)) * ldbb + (lane & 7) * 16;

#define STAGE(q, kt_) do {                                                            \
        _Pragma("unroll")                                                             \
        for (int p = 0; p < 4; ++p) {                                                 \
            gload_lds16(Agr + (size_t)(p * 8) * ldab + (size_t)(kt_) * 128,           \
                        lds + (q) * 65536 + w * 4096 + p * 1024);                     \
            gload_lds16(Bgr2 + (size_t)(p * 8) * ldbb + (size_t)(kt_) * 128,          \
                        lds + (q) * 65536 + 32768 + w * 4096 + p * 1024);             \
        }                                                                             \
    } while (0)

    f32x4 acc[8][4] = {};

    STAGE(0, 0);
    STAGE(1, 1);

    for (int kt = 0; kt < ktiles; ++kt) {
        const int cur = kt & 1;
        if (kt + 2 <= ktiles) { ASM_VMCNT8; } else { ASM_VMCNT0; }
        __builtin_amdgcn_s_barrier();
        __builtin_amdgcn_sched_barrier(0);
        const char* As = lds + cur * 65536;
        const char* Bs = lds + cur * 65536 + 32768;
#pragma unroll
        for (int kk = 0; kk < 2; ++kk) {
            short8 af[8], bfr[4];
#pragma unroll
            for (int mt = 0; mt < 8; ++mt) {
                int r = wm + mt * 16 + ml;
                af[mt] = *reinterpret_cast<const short8*>(
                    As + r * 128 + ((((kk << 2) | g) ^ (r & 7)) << 4));
            }
#pragma unroll
            for (int nt = 0; nt < 4; ++nt) {
                int r = wn + nt * 16 + ml;
                bfr[nt] = *reinterpret_cast<const short8*>(
                    Bs + r * 128 + ((((kk << 2) | g) ^ (r & 7)) << 4));
            }
            __builtin_amdgcn_s_setprio(1);
#pragma unroll
            for (int mt = 0; mt < 8; ++mt)
#pragma unroll
                for (int nt = 0; nt < 4; ++nt)
                    acc[mt][nt] = __builtin_amdgcn_mfma_f32_16x16x32_bf16(af[mt], bfr[nt], acc[mt][nt], 0, 0, 0);
            __builtin_amdgcn_s_setprio(0);
        }
        ASM_LGKM0;
        __builtin_amdgcn_s_barrier();   // all reads of buf[cur] done
        if (kt + 2 < ktiles) STAGE(cur, kt + 2);
    }

    // ---------------- epilogue ----------------
    if (OUT_MODE == 0) {
        float* O = (float*)Cout;
#pragma unroll
        for (int mt = 0; mt < 8; ++mt)
#pragma unroll
            for (int nt = 0; nt < 4; ++nt)
#pragma unroll
                for (int r_ = 0; r_ < 4; ++r_) {
                    int grow = bm * 256 + wm + mt * 16 + g * 4 + r_;
                    int gcol = bn * 256 + wn + nt * 16 + ml;
                    O[(size_t)grow * 512 + gcol] = acc[mt][nt][r_];
                }
    } else {
        // write Bu (bf16, packed cols) + dump tile to LDS for fused chunk-carry
        unsigned short* BuOut = (unsigned short*)Cout;
#pragma unroll
        for (int mt = 0; mt < 8; ++mt)
#pragma unroll
            for (int nt = 0; nt < 4; ++nt)
#pragma unroll
                for (int r_ = 0; r_ < 4; ++r_) {
                    int lrow = wm + mt * 16 + g * 4 + r_;
                    int lcol = wn + nt * 16 + ml;
                    unsigned short hv = f2bf(acc[mt][nt][r_]);
                    *(unsigned short*)(lds + lrow * 512 + lcol * 2) = hv;
                    BuOut[(size_t)(bm * 256 + lrow) * 1024 + bn * 256 + lcol] = hv;
                }
        ASM_LGKM0;
        __builtin_amdgcn_s_barrier();
        __builtin_amdgcn_sched_barrier(0);
        // 512 chains: 4 local chunks x 128 n-pairs
        int n_local = tid & 127, c_local = tid >> 7;
        int nglob = bn * 128 + n_local;
        float mod = expf(-expf(nu_log[nglob]));
        float th = expf(theta_log[nglob]);
        float s, co;
        sincosf(th, &s, &co);
        float Lre = mod * co, Lim = mod * s;
        const char* base = lds + (c_local * 64) * 512 + n_local * 4;
        float xr = 0.f, xi = 0.f;
#pragma unroll 8
        for (int t = 0; t < 64; ++t) {
            unsigned wv = *reinterpret_cast<const unsigned*>(base + t * 512);
            float nr = fmaf(Lre, xr, fmaf(-Lim, xi, bflo(wv)));
            float ni = fmaf(Lre, xi, fmaf(Lim, xr, bfhi(wv)));
            xr = nr; xi = ni;
        }
        int b = (bm * 256) >> 12;
        int cglob = (((bm * 256) & 4095) >> 6) + c_local;
        carry[(size_t)(b * NCHUNK + cglob) * 512 + nglob] = make_float2(xr, xi);
    }
#undef STAGE
}

// ---------------- scan (prefix over chunk carries, then apply) ----------------
__global__ void scan_prefix(const float2* __restrict__ carry, const float* __restrict__ nu_log,
                            const float* __restrict__ theta_log, float2* __restrict__ prefix) {
    int q = blockIdx.x * 256 + threadIdx.x;  // < 8192
    int n = q & 511, b = q >> 9;
    float e = expf(nu_log[n]);
    float modL = expf(-(float)CHUNK * e);
    float th = expf(theta_log[n]);
    double ang = fmod((double)CHUNK * (double)th, 6.283185307179586);
    float s, co;
    sincosf((float)ang, &s, &co);
    float Lre = modL * co, Lim = modL * s;
    float pr = 0.f, pi = 0.f;
    for (int c = 0; c < NCHUNK; ++c) {
        size_t idx = (size_t)(b * NCHUNK + c) * 512 + n;
        prefix[idx] = make_float2(pr, pi);
        float2 ev = carry[idx];
        float nr = fmaf(Lre, pr, fmaf(-Lim, pi, ev.x));
        float ni = fmaf(Lre, pi, fmaf(Lim, pr, ev.y));
        pr = nr; pi = ni;
    }
}

__global__ void scan_apply(const unsigned* __restrict__ Bu, const float* __restrict__ nu_log,
                           const float* __restrict__ theta_log, const float2* __restrict__ prefix,
                           char* __restrict__ Apack) {
    int q = blockIdx.x * 256 + threadIdx.x;
    int n = q & 511, c = (q >> 9) & 63, b = q >> 15;
    float mod = expf(-expf(nu_log[n]));
    float th = expf(theta_log[n]);
    float s, co;
    sincosf(th, &s, &co);
    float Lre = mod * co, Lim = mod * s;
    const unsigned* p = Bu + ((size_t)(b * TDIM + c * CHUNK)) * 512 + n;
    float2 pv = prefix[(size_t)(b * NCHUNK + c) * 512 + n];
    float xr = pv.x, xi = pv.y;
    int kp = (2 * n) & 63;
    int kk = kp >> 5, km = kp & 31;
    int half = km >> 4, gg = (km & 15) >> 2, j = km & 3;
    int cc = (kk << 2) | gg;
    int partial = (n >> 5) * 128 + half * 8 + j * 2;
    int row0 = b * TDIM + c * CHUNK;
#pragma unroll 8
    for (int t = 0; t < CHUNK; ++t) {
        unsigned wv = p[(size_t)t * 512];
        float nr = fmaf(Lre, xr, fmaf(-Lim, xi, bflo(wv)));
        float ni = fmaf(Lre, xi, fmaf(Lim, xr, bfhi(wv)));
        xr = nr; xi = ni;
        int row = row0 + t;
        size_t off = (size_t)row * 3072 + ((cc ^ (row & 7)) << 4) + partial;
        *reinterpret_cast<unsigned*>(Apack + off) =
            (unsigned)f2bf(xr) | ((unsigned)f2bf(xi) << 16);
    }
}

extern "C" void kernel_launch(void* const* d_in, const int* in_sizes, int n_in,
                              void* d_out, int out_size, void* d_ws, size_t ws_size,
                              hipStream_t stream) {
    const float* u         = (const float*)d_in[0];
    const float* nu_log    = (const float*)d_in[1];
    const float* theta_log = (const float*)d_in[2];
    const float* gamma_log = (const float*)d_in[3];
    const float* B_re      = (const float*)d_in[4];
    const float* B_im      = (const float*)d_in[5];
    const float* C_re      = (const float*)d_in[6];
    const float* C_im      = (const float*)d_in[7];
    const float* D         = (const float*)d_in[8];

    char* ws = (char*)d_ws;
    char* Apack = ws;                                   // 65536*3072 B = 201 MB (perm layout)
    size_t off = (size_t)MTOT * 3072;
    char* W1 = ws + off; off += 1024 * 1024;            // 1 MB
    char* W2 = ws + off; off += 512 * 3072;             // 1.5 MB
    float2* carry  = (float2*)(ws + off); off += (size_t)BDIM * NCHUNK * 512 * 8;
    float2* prefix = (float2*)(ws + off); off += (size_t)BDIM * NCHUNK * 512 * 8;

    unsigned short* Bu = (unsigned short*)d_out;  // 65536*1024 ushort == out bytes

    prep_w1<<<dim3(2, 1024), 256, 0, stream>>>(B_re, B_im, gamma_log, W1);
    prep_w2<<<dim3(6, 512), 256, 0, stream>>>(C_re, C_im, D, W2);
    convert_u<<<32768, 256, 0, stream>>>((const float4*)u, Apack);
    // GEMM1: Bu = u_bf16 . W1^T  (M=65536, N=1024, K=512) + fused chunk-carry
    gemm_nt<1, 4><<<1024, 512, 0, stream>>>(Apack + 16 * 128, 3072, W1, 1024,
                                            (void*)Bu, 8, carry, nu_log, theta_log);
    scan_prefix<<<32, 256, 0, stream>>>(carry, nu_log, theta_log, prefix);
    scan_apply<<<2048, 256, 0, stream>>>((const unsigned*)Bu, nu_log, theta_log, prefix, Apack);
    // GEMM2: y = Apack . W2^T  (M=65536, N=512, K=1536), f32 out
    gemm_nt<0, 2><<<512, 512, 0, stream>>>(Apack, 3072, W2, 3072, d_out, 24,
                                           nullptr, nullptr, nullptr);
}

// Round 4
// 309.495 us; speedup vs baseline: 3.5954x; 1.0346x over previous
//
#include <hip/hip_runtime.h>
#include <hip/hip_bf16.h>
#include <cstdint>
#include <cstddef>

// LRU forward: B=16, T=4096, IN=OUT=N=512
// prep weights (bf16, perm layout) -> convert u -> GEMM1 (Bu, 256^2 4-phase
// counted-vmcnt pipeline, carry fused in epilogue) -> prefix -> apply -> GEMM2.
// d_out doubles as scratch for Bu before y overwrites it.
//
// Perm layout: row-major rows; each 64-k tile is 128 B = 8 chunks of 16 B.
// Chunk c at row r holds fragment chunk cc = c ^ (r&7) (XOR bank swizzle);
// fragment chunk cc = kk*4+g holds k = {kk*32+g*4+j, kk*32+16+g*4+j}, so one
// ds_read_b128 = one MFMA operand fragment, conflict-free; global_load_lds
// staging stays plain contiguous 16B chunks (LDS linear).

using short8 = __attribute__((ext_vector_type(8))) short;
using f32x4 = __attribute__((ext_vector_type(4))) float;

#define BDIM 16
#define TDIM 4096
#define MTOT (BDIM * TDIM)   // 65536
#define CHUNK 64
#define NCHUNK (TDIM / CHUNK) // 64

__device__ __forceinline__ unsigned short f2bf(float f) {
    unsigned u = __float_as_uint(f);
    u = u + 0x7FFFu + ((u >> 16) & 1u);   // RNE
    return (unsigned short)(u >> 16);
}
__device__ __forceinline__ float bflo(unsigned w) { return __uint_as_float(w << 16); }
__device__ __forceinline__ float bfhi(unsigned w) { return __uint_as_float(w & 0xFFFF0000u); }

__device__ __forceinline__ size_t perm_off(int row, int kt, int kp, int rowbytes) {
    int kk = kp >> 5, km = kp & 31;
    int half = km >> 4;
    int g = (km & 15) >> 2, j = km & 3;
    int cc = (kk << 2) | g;
    int c = cc ^ (row & 7);
    return (size_t)row * rowbytes + kt * 128 + (c << 4) + half * 8 + j * 2;
}

__device__ __forceinline__ void gload_lds16(const void* g, void* l) {
    __builtin_amdgcn_global_load_lds((const __attribute__((address_space(1))) void*)g,
                                     (__attribute__((address_space(3))) void*)l, 16, 0, 0);
}

// ---------------- weight prep ----------------
__global__ void prep_w1(const float* __restrict__ B_re, const float* __restrict__ B_im,
                        const float* __restrict__ gamma_log, char* __restrict__ W1) {
    int i = blockIdx.x * 256 + threadIdx.x;  // 0..511 (k)
    int r = blockIdx.y;                      // 0..1023 (row)
    int n = r >> 1;
    float gmm = expf(gamma_log[n]);
    float v = (r & 1) ? B_im[n * 512 + i] * gmm : B_re[n * 512 + i] * gmm;
    *(unsigned short*)(W1 + perm_off(r, i >> 6, i & 63, 1024)) = f2bf(v);
}

__global__ void prep_w2(const float* __restrict__ C_re, const float* __restrict__ C_im,
                        const float* __restrict__ D, char* __restrict__ W2) {
    int k = blockIdx.x * 256 + threadIdx.x;  // 0..1535
    int o = blockIdx.y;                      // 0..511
    float v;
    if (k < 1024) {
        int n = k >> 1;
        v = (k & 1) ? -2.0f * C_im[o * 512 + n] : 2.0f * C_re[o * 512 + n];
    } else {
        v = D[o * 512 + (k - 1024)];
    }
    *(unsigned short*)(W2 + perm_off(o, k >> 6, k & 63, 3072)) = f2bf(v);
}

__global__ void convert_u(const float4* __restrict__ u4, char* __restrict__ Apack) {
    size_t idx = (size_t)blockIdx.x * 256 + threadIdx.x;  // < 65536*128
    float4 v = u4[idx];
    int row = (int)(idx >> 7);
    int c4 = (int)(idx & 127);
    int kg = 1024 + c4 * 4;
    unsigned lo = (unsigned)f2bf(v.x) | ((unsigned)f2bf(v.y) << 16);
    unsigned hi = (unsigned)f2bf(v.z) | ((unsigned)f2bf(v.w) << 16);
    size_t off = perm_off(row, kg >> 6, kg & 63, 3072);
    *reinterpret_cast<uint2*>(Apack + off) = make_uint2(lo, hi);
}

// ---------------- 256x256 4-phase pipelined MFMA GEMM (NT, perm layout) --------
// 8 waves (2M x 4N), BK=64, double-buffered 128 KB LDS, counted vmcnt, setprio.
// OUT_MODE 0: f32 C (ld 512). OUT_MODE 1: bf16 Bu (ld 1024) + fused chunk-carry.
#define ASM_VMCNT2 asm volatile("s_waitcnt vmcnt(2)" ::: "memory")
#define ASM_VMCNT0 asm volatile("s_waitcnt vmcnt(0)" ::: "memory")
#define ASM_LGKM0  asm volatile("s_waitcnt lgkmcnt(0)" ::: "memory")
#define SCHED0     __builtin_amdgcn_sched_barrier(0)
#define BARRIER    __builtin_amdgcn_s_barrier()

template <int OUT_MODE, int NBN>
__global__ __launch_bounds__(512, 2) void gemm_nt(const char* __restrict__ A, int ldab,
                                                  const char* __restrict__ Bm, int ldbb,
                                                  void* __restrict__ Cout, int ktiles,
                                                  float2* __restrict__ carry,
                                                  const float* __restrict__ nu_log,
                                                  const float* __restrict__ theta_log) {
    __shared__ __align__(16) char lds[131072];  // [buf0: A|B][buf1: A|B], 32 KB each
    const int tid = threadIdx.x;
    const int lane = tid & 63, w = tid >> 6;
    const int bid = blockIdx.x;
    const int cpx = gridDim.x >> 3;             // grid divisible by 8
    const int swz = (bid & 7) * cpx + (bid >> 3);
    const int bm = swz / NBN, bn = swz % NBN;
    const int wm = (w >> 2) * 128, wn = (w & 3) * 64;
    const int ml = lane & 15, g = lane >> 4;

    const char* Agr = A + (size_t)(bm * 256 + w * 32 + (lane >> 3)) * ldab + (lane & 7) * 16;
    const char* Bgr = Bm + (size_t)(bn * 256 + w * 32 + (lane >> 3)) * ldbb + (lane & 7) * 16;

#define STAGE_P(q, kt_, p) do {                                                       \
        gload_lds16(Agr + (size_t)((p) * 8) * ldab + (size_t)(kt_) * 128,             \
                    lds + (q) * 65536 + w * 4096 + (p) * 1024);                       \
        gload_lds16(Bgr + (size_t)((p) * 8) * ldbb + (size_t)(kt_) * 128,             \
                    lds + (q) * 65536 + 32768 + w * 4096 + (p) * 1024);               \
    } while (0)

#define RD_A(arr, mtb, mt, kk) do {                                                   \
        int r_ = wm + ((mtb) + (mt)) * 16 + ml;                                       \
        arr[mt][kk] = *reinterpret_cast<const short8*>(                               \
            As + r_ * 128 + (((((kk) << 2) | g) ^ (r_ & 7)) << 4));                   \
    } while (0)

#define RD_B(nt, kk) do {                                                             \
        int r_ = wn + (nt) * 16 + ml;                                                 \
        bfv[nt][kk] = *reinterpret_cast<const short8*>(                               \
            Bs + r_ * 128 + (((((kk) << 2) | g) ^ (r_ & 7)) << 4));                   \
    } while (0)

#define MFMA_Q(arr, mtb, ntb)                                                         \
    _Pragma("unroll")                                                                 \
    for (int mt = 0; mt < 4; ++mt)                                                    \
    _Pragma("unroll")                                                                 \
    for (int nt = 0; nt < 2; ++nt)                                                    \
    _Pragma("unroll")                                                                 \
    for (int kk = 0; kk < 2; ++kk)                                                    \
        acc[(mtb) + mt][(ntb) + nt] = __builtin_amdgcn_mfma_f32_16x16x32_bf16(        \
            arr[mt][kk], bfv[(ntb) + nt][kk], acc[(mtb) + mt][(ntb) + nt], 0, 0, 0)

    f32x4 acc[8][4] = {};
    short8 afA[4][2], afB[4][2], bfv[4][2];

    // prologue: fully stage buf0 (8 gloads/wave)
#pragma unroll
    for (int p = 0; p < 4; ++p) STAGE_P(0, 0, p);

    for (int kt = 0; kt < ktiles; ++kt) {
        const int cur = kt & 1, nq = cur ^ 1;
        const char* As = lds + cur * 65536;
        const char* Bs = As + 32768;
        const bool pre = (kt + 1 < ktiles);
        // ---- tile top: confirm buf[cur] staged (counted wait), join waves
        if (pre) { STAGE_P(nq, kt + 1, 0); ASM_VMCNT2; } else { ASM_VMCNT0; }
        SCHED0;
        BARRIER;
        // ---- P0: quadrant (m0..3, n0..1)
#pragma unroll
        for (int mt = 0; mt < 4; ++mt) { RD_A(afA, 0, mt, 0); RD_A(afA, 0, mt, 1); }
        RD_B(0, 0); RD_B(0, 1); RD_B(1, 0); RD_B(1, 1);
        if (pre) STAGE_P(nq, kt + 1, 1);
        SCHED0; BARRIER; ASM_LGKM0; SCHED0;
        __builtin_amdgcn_s_setprio(1);
        MFMA_Q(afA, 0, 0);
        __builtin_amdgcn_s_setprio(0);
        BARRIER;
        // ---- P1: quadrant (m0..3, n2..3)
        RD_B(2, 0); RD_B(2, 1); RD_B(3, 0); RD_B(3, 1);
        if (pre) STAGE_P(nq, kt + 1, 2);
        SCHED0; BARRIER; ASM_LGKM0; SCHED0;
        __builtin_amdgcn_s_setprio(1);
        MFMA_Q(afA, 0, 2);
        __builtin_amdgcn_s_setprio(0);
        BARRIER;
        // ---- P2: quadrant (m4..7, n0..1)
#pragma unroll
        for (int mt = 0; mt < 4; ++mt) { RD_A(afB, 4, mt, 0); RD_A(afB, 4, mt, 1); }
        if (pre) STAGE_P(nq, kt + 1, 3);
        SCHED0; BARRIER; ASM_LGKM0; SCHED0;
        __builtin_amdgcn_s_setprio(1);
        MFMA_Q(afB, 4, 0);
        __builtin_amdgcn_s_setprio(0);
        BARRIER;
        // ---- P3: quadrant (m4..7, n2..3); no reads, no stage; trailing barrier
        // merges into next tile-top barrier (stage of next top writes a buffer
        // whose reads all drained at P2's lgkm0+barrier).
        SCHED0;
        __builtin_amdgcn_s_setprio(1);
        MFMA_Q(afB, 4, 2);
        __builtin_amdgcn_s_setprio(0);
    }

    // ---------------- epilogue ----------------
    if (OUT_MODE == 0) {
        float* O = (float*)Cout;
#pragma unroll
        for (int mt = 0; mt < 8; ++mt)
#pragma unroll
            for (int nt = 0; nt < 4; ++nt)
#pragma unroll
                for (int r_ = 0; r_ < 4; ++r_) {
                    int grow = bm * 256 + wm + mt * 16 + g * 4 + r_;
                    int gcol = bn * 256 + wn + nt * 16 + ml;
                    O[(size_t)grow * 512 + gcol] = acc[mt][nt][r_];
                }
    } else {
        // write Bu (bf16, packed cols) + dump tile to LDS for fused chunk-carry
        unsigned short* BuOut = (unsigned short*)Cout;
#pragma unroll
        for (int mt = 0; mt < 8; ++mt)
#pragma unroll
            for (int nt = 0; nt < 4; ++nt)
#pragma unroll
                for (int r_ = 0; r_ < 4; ++r_) {
                    int lrow = wm + mt * 16 + g * 4 + r_;
                    int lcol = wn + nt * 16 + ml;
                    unsigned short hv = f2bf(acc[mt][nt][r_]);
                    *(unsigned short*)(lds + lrow * 512 + lcol * 2) = hv;
                    BuOut[(size_t)(bm * 256 + lrow) * 1024 + bn * 256 + lcol] = hv;
                }
        ASM_LGKM0;
        BARRIER;
        SCHED0;
        // 512 chains: 4 local chunks x 128 n-pairs
        int n_local = tid & 127, c_local = tid >> 7;
        int nglob = bn * 128 + n_local;
        float mod = expf(-expf(nu_log[nglob]));
        float th = expf(theta_log[nglob]);
        float s, co;
        sincosf(th, &s, &co);
        float Lre = mod * co, Lim = mod * s;
        const char* base = lds + (c_local * 64) * 512 + n_local * 4;
        float xr = 0.f, xi = 0.f;
#pragma unroll 8
        for (int t = 0; t < 64; ++t) {
            unsigned wv = *reinterpret_cast<const unsigned*>(base + t * 512);
            float nr = fmaf(Lre, xr, fmaf(-Lim, xi, bflo(wv)));
            float ni = fmaf(Lre, xi, fmaf(Lim, xr, bfhi(wv)));
            xr = nr; xi = ni;
        }
        int b = (bm * 256) >> 12;
        int cglob = (((bm * 256) & 4095) >> 6) + c_local;
        carry[(size_t)(b * NCHUNK + cglob) * 512 + nglob] = make_float2(xr, xi);
    }
#undef STAGE_P
#undef RD_A
#undef RD_B
#undef MFMA_Q
}

// ---------------- scan (prefix over chunk carries, then apply) ----------------
__global__ void scan_prefix(const float2* __restrict__ carry, const float* __restrict__ nu_log,
                            const float* __restrict__ theta_log, float2* __restrict__ prefix) {
    int q = blockIdx.x * 256 + threadIdx.x;  // < 8192
    int n = q & 511, b = q >> 9;
    float e = expf(nu_log[n]);
    float modL = expf(-(float)CHUNK * e);
    float th = expf(theta_log[n]);
    double ang = fmod((double)CHUNK * (double)th, 6.283185307179586);
    float s, co;
    sincosf((float)ang, &s, &co);
    float Lre = modL * co, Lim = modL * s;
    float pr = 0.f, pi = 0.f;
    for (int c = 0; c < NCHUNK; ++c) {
        size_t idx = (size_t)(b * NCHUNK + c) * 512 + n;
        prefix[idx] = make_float2(pr, pi);
        float2 ev = carry[idx];
        float nr = fmaf(Lre, pr, fmaf(-Lim, pi, ev.x));
        float ni = fmaf(Lre, pi, fmaf(Lim, pr, ev.y));
        pr = nr; pi = ni;
    }
}

__global__ void scan_apply(const unsigned* __restrict__ Bu, const float* __restrict__ nu_log,
                           const float* __restrict__ theta_log, const float2* __restrict__ prefix,
                           char* __restrict__ Apack) {
    int q = blockIdx.x * 256 + threadIdx.x;
    int n = q & 511, c = (q >> 9) & 63, b = q >> 15;
    float mod = expf(-expf(nu_log[n]));
    float th = expf(theta_log[n]);
    float s, co;
    sincosf(th, &s, &co);
    float Lre = mod * co, Lim = mod * s;
    const unsigned* p = Bu + ((size_t)(b * TDIM + c * CHUNK)) * 512 + n;
    float2 pv = prefix[(size_t)(b * NCHUNK + c) * 512 + n];
    float xr = pv.x, xi = pv.y;
    int kp = (2 * n) & 63;
    int kk = kp >> 5, km = kp & 31;
    int half = km >> 4, gg = (km & 15) >> 2, j = km & 3;
    int cc = (kk << 2) | gg;
    int partial = (n >> 5) * 128 + half * 8 + j * 2;
    int row0 = b * TDIM + c * CHUNK;
#pragma unroll 8
    for (int t = 0; t < CHUNK; ++t) {
        unsigned wv = p[(size_t)t * 512];
        float nr = fmaf(Lre, xr, fmaf(-Lim, xi, bflo(wv)));
        float ni = fmaf(Lre, xi, fmaf(Lim, xr, bfhi(wv)));
        xr = nr; xi = ni;
        int row = row0 + t;
        size_t off = (size_t)row * 3072 + ((cc ^ (row & 7)) << 4) + partial;
        *reinterpret_cast<unsigned*>(Apack + off) =
            (unsigned)f2bf(xr) | ((unsigned)f2bf(xi) << 16);
    }
}

extern "C" void kernel_launch(void* const* d_in, const int* in_sizes, int n_in,
                              void* d_out, int out_size, void* d_ws, size_t ws_size,
                              hipStream_t stream) {
    const float* u         = (const float*)d_in[0];
    const float* nu_log    = (const float*)d_in[1];
    const float* theta_log = (const float*)d_in[2];
    const float* gamma_log = (const float*)d_in[3];
    const float* B_re      = (const float*)d_in[4];
    const float* B_im      = (const float*)d_in[5];
    const float* C_re      = (const float*)d_in[6];
    const float* C_im      = (const float*)d_in[7];
    const float* D         = (const float*)d_in[8];

    char* ws = (char*)d_ws;
    char* Apack = ws;                                   // 65536*3072 B = 201 MB (perm layout)
    size_t off = (size_t)MTOT * 3072;
    char* W1 = ws + off; off += 1024 * 1024;            // 1 MB
    char* W2 = ws + off; off += 512 * 3072;             // 1.5 MB
    float2* carry  = (float2*)(ws + off); off += (size_t)BDIM * NCHUNK * 512 * 8;
    float2* prefix = (float2*)(ws + off); off += (size_t)BDIM * NCHUNK * 512 * 8;

    unsigned short* Bu = (unsigned short*)d_out;  // 65536*1024 ushort == out bytes

    prep_w1<<<dim3(2, 1024), 256, 0, stream>>>(B_re, B_im, gamma_log, W1);
    prep_w2<<<dim3(6, 512), 256, 0, stream>>>(C_re, C_im, D, W2);
    convert_u<<<32768, 256, 0, stream>>>((const float4*)u, Apack);
    // GEMM1: Bu = u_bf16 . W1^T  (M=65536, N=1024, K=512) + fused chunk-carry
    gemm_nt<1, 4><<<1024, 512, 0, stream>>>(Apack + 16 * 128, 3072, W1, 1024,
                                            (void*)Bu, 8, carry, nu_log, theta_log);
    scan_prefix<<<32, 256, 0, stream>>>(carry, nu_log, theta_log, prefix);
    scan_apply<<<2048, 256, 0, stream>>>((const unsigned*)Bu, nu_log, theta_log, prefix, Apack);
    // GEMM2: y = Apack . W2^T  (M=65536, N=512, K=1536), f32 out
    gemm_nt<0, 2><<<512, 512, 0, stream>>>(Apack, 3072, W2, 3072, d_out, 24,
                                           nullptr, nullptr, nullptr);
}

// Round 6
// 294.689 us; speedup vs baseline: 3.7760x; 1.0502x over previous
//
#include <hip/hip_runtime.h>
#include <hip/hip_bf16.h>
#include <cstdint>
#include <cstddef>

// LRU forward: B=16, T=4096, IN=OUT=N=512
// prep weights (bf16, perm layout) -> convert u -> GEMM1 (Bu, 256^2 8-phase
// counted-vmcnt pipeline, carry fused in epilogue) -> prefix -> apply -> GEMM2.
// d_out doubles as scratch for Bu before y overwrites it.
//
// Perm layout: row-major rows; each 64-k tile is 128 B = 8 chunks of 16 B.
// Chunk c at row r holds fragment chunk cc = c ^ (r&7) (XOR bank swizzle);
// fragment chunk cc = kk*4+g holds k = {kk*32+g*4+j, kk*32+16+g*4+j}, so one
// ds_read_b128 = one MFMA operand fragment, conflict-free; global_load_lds
// staging stays plain contiguous 16B chunks (LDS linear).

using short8 = __attribute__((ext_vector_type(8))) short;
using f32x4 = __attribute__((ext_vector_type(4))) float;

#define BDIM 16
#define TDIM 4096
#define MTOT (BDIM * TDIM)   // 65536
#define CHUNK 64
#define NCHUNK (TDIM / CHUNK) // 64

__device__ __forceinline__ unsigned short f2bf(float f) {
    unsigned u = __float_as_uint(f);
    u = u + 0x7FFFu + ((u >> 16) & 1u);   // RNE
    return (unsigned short)(u >> 16);
}
__device__ __forceinline__ float bflo(unsigned w) { return __uint_as_float(w << 16); }
__device__ __forceinline__ float bfhi(unsigned w) { return __uint_as_float(w & 0xFFFF0000u); }

__device__ __forceinline__ size_t perm_off(int row, int kt, int kp, int rowbytes) {
    int kk = kp >> 5, km = kp & 31;
    int half = km >> 4;
    int g = (km & 15) >> 2, j = km & 3;
    int cc = (kk << 2) | g;
    int c = cc ^ (row & 7);
    return (size_t)row * rowbytes + kt * 128 + (c << 4) + half * 8 + j * 2;
}

__device__ __forceinline__ void gload_lds16(const void* g, void* l) {
    __builtin_amdgcn_global_load_lds((const __attribute__((address_space(1))) void*)g,
                                     (__attribute__((address_space(3))) void*)l, 16, 0, 0);
}

// ---------------- weight prep ----------------
__global__ void prep_w1(const float* __restrict__ B_re, const float* __restrict__ B_im,
                        const float* __restrict__ gamma_log, char* __restrict__ W1) {
    int i = blockIdx.x * 256 + threadIdx.x;  // 0..511 (k)
    int r = blockIdx.y;                      // 0..1023 (row)
    int n = r >> 1;
    float gmm = expf(gamma_log[n]);
    float v = (r & 1) ? B_im[n * 512 + i] * gmm : B_re[n * 512 + i] * gmm;
    *(unsigned short*)(W1 + perm_off(r, i >> 6, i & 63, 1024)) = f2bf(v);
}

__global__ void prep_w2(const float* __restrict__ C_re, const float* __restrict__ C_im,
                        const float* __restrict__ D, char* __restrict__ W2) {
    int k = blockIdx.x * 256 + threadIdx.x;  // 0..1535
    int o = blockIdx.y;                      // 0..511
    float v;
    if (k < 1024) {
        int n = k >> 1;
        v = (k & 1) ? -2.0f * C_im[o * 512 + n] : 2.0f * C_re[o * 512 + n];
    } else {
        v = D[o * 512 + (k - 1024)];
    }
    *(unsigned short*)(W2 + perm_off(o, k >> 6, k & 63, 3072)) = f2bf(v);
}

__global__ void convert_u(const float4* __restrict__ u4, char* __restrict__ Apack) {
    size_t idx = (size_t)blockIdx.x * 256 + threadIdx.x;  // < 65536*128
    float4 v = u4[idx];
    int row = (int)(idx >> 7);
    int c4 = (int)(idx & 127);
    int kg = 1024 + c4 * 4;
    unsigned lo = (unsigned)f2bf(v.x) | ((unsigned)f2bf(v.y) << 16);
    unsigned hi = (unsigned)f2bf(v.z) | ((unsigned)f2bf(v.w) << 16);
    size_t off = perm_off(row, kg >> 6, kg & 63, 3072);
    *reinterpret_cast<uint2*>(Apack + off) = make_uint2(lo, hi);
}

// ---------------- 256x256 8-phase pipelined MFMA GEMM (NT, perm layout) --------
// 8 waves (2M x 4N), BK=64, 2 K-tiles/iter, 8 phases/iter, half-tile staging.
// LDS per buffer q (64KB): A0 | A1 | B0 | B1, 16 KB each. buf(tile)=tile&1.
// vmcnt(4) at P4/P8-end (before closing barrier) -> next group's reads safe.
#define ASM_VMCNT4 asm volatile("s_waitcnt vmcnt(4)" ::: "memory")
#define ASM_VMCNT0 asm volatile("s_waitcnt vmcnt(0)" ::: "memory")
#define ASM_LGKM0  asm volatile("s_waitcnt lgkmcnt(0)" ::: "memory")
#define SCHED0     __builtin_amdgcn_sched_barrier(0)
#define BARRIER    __builtin_amdgcn_s_barrier()
#define PRIO1      __builtin_amdgcn_s_setprio(1)
#define PRIO0      __builtin_amdgcn_s_setprio(0)

template <int OUT_MODE, int NBN>
__global__ __launch_bounds__(512, 2) void gemm_nt(const char* __restrict__ A, int ldab,
                                                  const char* __restrict__ Bm, int ldbb,
                                                  void* __restrict__ Cout, int ktiles,
                                                  float2* __restrict__ carry,
                                                  const float* __restrict__ nu_log,
                                                  const float* __restrict__ theta_log) {
    __shared__ __align__(16) char lds[131072];
    const int tid = threadIdx.x;
    const int lane = tid & 63, w = tid >> 6;
    const int bid = blockIdx.x;
    const int cpx = gridDim.x >> 3;             // grid divisible by 8
    const int swz = (bid & 7) * cpx + (bid >> 3);
    const int bm = swz / NBN, bn = swz % NBN;
    const int wm = (w >> 2) * 128, wn = (w & 3) * 64;
    const int ml = lane & 15, g = lane >> 4;

    // staging source: wave w covers rows w*16 + j*8 + (lane>>3) of a 128-row half
    const char* AgrL = A + (size_t)(bm * 256 + w * 16 + (lane >> 3)) * ldab + (lane & 7) * 16;
    const char* BgrL = Bm + (size_t)(bn * 256 + w * 16 + (lane >> 3)) * ldbb + (lane & 7) * 16;

#define STG_A(h, kt_, q) do {                                                         \
        const char* s_ = AgrL + (size_t)((h) * 128) * ldab + (size_t)(kt_) * 128;     \
        char* d_ = lds + (q) * 65536 + (h) * 16384 + w * 2048;                        \
        gload_lds16(s_, d_);                                                          \
        gload_lds16(s_ + (size_t)8 * ldab, d_ + 1024);                                \
    } while (0)
#define STG_B(h, kt_, q) do {                                                         \
        const char* s_ = BgrL + (size_t)((h) * 128) * ldbb + (size_t)(kt_) * 128;     \
        char* d_ = lds + (q) * 65536 + 32768 + (h) * 16384 + w * 2048;                \
        gload_lds16(s_, d_);                                                          \
        gload_lds16(s_ + (size_t)8 * ldbb, d_ + 1024);                                \
    } while (0)

#define RD_A_(mh, Abase) do {                                                         \
        _Pragma("unroll") for (int mt = 0; mt < 4; ++mt)                              \
        _Pragma("unroll") for (int kk = 0; kk < 2; ++kk) {                            \
            int r_ = wm + (mh) * 64 + mt * 16 + ml;                                   \
            int hf_ = r_ >> 7, rl_ = r_ & 127;                                        \
            afr[mt][kk] = *reinterpret_cast<const short8*>(                           \
                (Abase) + hf_ * 16384 + rl_ * 128 + ((((kk << 2) | g) ^ (rl_ & 7)) << 4)); \
        } } while (0)
#define RD_B_(nh, Bbase) do {                                                         \
        _Pragma("unroll") for (int nt = 0; nt < 2; ++nt)                              \
        _Pragma("unroll") for (int kk = 0; kk < 2; ++kk) {                            \
            int c_ = wn + (nh) * 32 + nt * 16 + ml;                                   \
            int hf_ = c_ >> 7, cl_ = c_ & 127;                                        \
            bfr[nh][nt][kk] = *reinterpret_cast<const short8*>(                       \
                (Bbase) + hf_ * 16384 + cl_ * 128 + ((((kk << 2) | g) ^ (cl_ & 7)) << 4)); \
        } } while (0)

#define MFMA16(mh, nh)                                                                \
    _Pragma("unroll") for (int kk = 0; kk < 2; ++kk)                                  \
    _Pragma("unroll") for (int mt = 0; mt < 4; ++mt)                                  \
    _Pragma("unroll") for (int nt = 0; nt < 2; ++nt)                                  \
        acc[(mh) * 4 + mt][(nh) * 2 + nt] = __builtin_amdgcn_mfma_f32_16x16x32_bf16(  \
            afr[mt][kk], bfr[nh][nt][kk], acc[(mh) * 4 + mt][(nh) * 2 + nt], 0, 0, 0)

    f32x4 acc[8][4] = {};
    short8 afr[4][2];
    short8 bfr[2][2][2];

    const char* A0b = lds;
    const char* B0b = lds + 32768;
    const char* A1b = lds + 65536;
    const char* B1b = lds + 98304;

    // prologue: tile0 full (buf0, 8 loads oldest) + tile1.B0,B1 (buf1, 4 loads)
    STG_A(0, 0, 0); STG_A(1, 0, 0); STG_B(0, 0, 0); STG_B(1, 0, 0);
    STG_B(0, 1, 1); STG_B(1, 1, 1);
    ASM_VMCNT4;   // tile0's 8 loads done; tile1.B pending
    BARRIER;      // cross-wave: all of tile0 staged

    const int NT = ktiles >> 1;
    for (int it = 0; it < NT; ++it) {
        const int t1i = 2 * it + 1, t2i = 2 * it + 2, t3i = 2 * it + 3;
        const bool more = (t2i < ktiles);
        // ---- P1: Q(m0,n0) of tile 2i (buf0); stage t1.A0 -> buf1
        RD_A_(0, A0b); RD_B_(0, B0b);
        STG_A(0, t1i, 1);
        BARRIER; ASM_LGKM0; SCHED0;
        PRIO1; MFMA16(0, 0); PRIO0;
        BARRIER;
        // ---- P2: Q(m0,n1); stage t1.A1 -> buf1
        RD_B_(1, B0b);
        STG_A(1, t1i, 1);
        BARRIER; ASM_LGKM0; SCHED0;
        PRIO1; MFMA16(0, 1); PRIO0;
        BARRIER;
        // ---- P3: Q(m1,n0); stage t2.B0 -> buf0 (B0 free after P2)
        RD_A_(1, A0b);
        if (more) STG_B(0, t2i, 0);
        BARRIER; ASM_LGKM0; SCHED0;
        PRIO1; MFMA16(1, 0); PRIO0;
        BARRIER;
        // ---- P4: Q(m1,n1); stage t2.B1 -> buf0; counted wait for tile t1
        if (more) STG_B(1, t2i, 0);
        PRIO1; MFMA16(1, 1); PRIO0;
        if (more) { ASM_VMCNT4; } else { ASM_VMCNT0; }
        BARRIER;   // cross-wave: all of tile 2i+1 staged
        // ---- P5: Q(m0,n0) of tile 2i+1 (buf1); stage t2.A0 -> buf0 (free after P3)
        RD_A_(0, A1b); RD_B_(0, B1b);
        if (more) STG_A(0, t2i, 0);
        BARRIER; ASM_LGKM0; SCHED0;
        PRIO1; MFMA16(0, 0); PRIO0;
        BARRIER;
        // ---- P6: Q(m0,n1); stage t2.A1 -> buf0
        RD_B_(1, B1b);
        if (more) STG_A(1, t2i, 0);
        BARRIER; ASM_LGKM0; SCHED0;
        PRIO1; MFMA16(0, 1); PRIO0;
        BARRIER;
        // ---- P7: Q(m1,n0); stage t3.B0 -> buf1 (B free after P6)
        RD_A_(1, A1b);
        if (more) STG_B(0, t3i, 1);
        BARRIER; ASM_LGKM0; SCHED0;
        PRIO1; MFMA16(1, 0); PRIO0;
        BARRIER;
        // ---- P8: Q(m1,n1); stage t3.B1 -> buf1; counted wait for tile t2
        if (more) STG_B(1, t3i, 1);
        PRIO1; MFMA16(1, 1); PRIO0;
        if (more) { ASM_VMCNT4; }
        BARRIER;   // cross-wave: tile 2i+2 staged (when more)
    }

    // ---------------- epilogue ----------------
    if (OUT_MODE == 0) {
        float* O = (float*)Cout;
#pragma unroll
        for (int mt = 0; mt < 8; ++mt)
#pragma unroll
            for (int nt = 0; nt < 4; ++nt)
#pragma unroll
                for (int r_ = 0; r_ < 4; ++r_) {
                    int grow = bm * 256 + wm + mt * 16 + g * 4 + r_;
                    int gcol = bn * 256 + wn + nt * 16 + ml;
                    O[(size_t)grow * 512 + gcol] = acc[mt][nt][r_];
                }
    } else {
        // write Bu (bf16, packed cols) + dump tile to LDS for fused chunk-carry
        unsigned short* BuOut = (unsigned short*)Cout;
#pragma unroll
        for (int mt = 0; mt < 8; ++mt)
#pragma unroll
            for (int nt = 0; nt < 4; ++nt)
#pragma unroll
                for (int r_ = 0; r_ < 4; ++r_) {
                    int lrow = wm + mt * 16 + g * 4 + r_;
                    int lcol = wn + nt * 16 + ml;
                    unsigned short hv = f2bf(acc[mt][nt][r_]);
                    *(unsigned short*)(lds + lrow * 512 + lcol * 2) = hv;
                    BuOut[(size_t)(bm * 256 + lrow) * 1024 + bn * 256 + lcol] = hv;
                }
        ASM_LGKM0;
        BARRIER;
        SCHED0;
        // 512 chains: 4 local chunks x 128 n-pairs
        int n_local = tid & 127, c_local = tid >> 7;
        int nglob = bn * 128 + n_local;
        float mod = expf(-expf(nu_log[nglob]));
        float th = expf(theta_log[nglob]);
        float s, co;
        sincosf(th, &s, &co);
        float Lre = mod * co, Lim = mod * s;
        const char* base = lds + (c_local * 64) * 512 + n_local * 4;
        float xr = 0.f, xi = 0.f;
#pragma unroll 8
        for (int t = 0; t < 64; ++t) {
            unsigned wv = *reinterpret_cast<const unsigned*>(base + t * 512);
            float nr = fmaf(Lre, xr, fmaf(-Lim, xi, bflo(wv)));
            float ni = fmaf(Lre, xi, fmaf(Lim, xr, bfhi(wv)));
            xr = nr; xi = ni;
        }
        int b = (bm * 256) >> 12;
        int cglob = (((bm * 256) & 4095) >> 6) + c_local;
        carry[(size_t)(b * NCHUNK + cglob) * 512 + nglob] = make_float2(xr, xi);
    }
#undef STG_A
#undef STG_B
#undef RD_A_
#undef RD_B_
#undef MFMA16
}

// ---------------- scan (prefix over chunk carries, then apply) ----------------
__global__ void scan_prefix(const float2* __restrict__ carry, const float* __restrict__ nu_log,
                            const float* __restrict__ theta_log, float2* __restrict__ prefix) {
    int q = blockIdx.x * 256 + threadIdx.x;  // < 8192
    int n = q & 511, b = q >> 9;
    float e = expf(nu_log[n]);
    float modL = expf(-(float)CHUNK * e);
    float th = expf(theta_log[n]);
    double ang = fmod((double)CHUNK * (double)th, 6.283185307179586);
    float s, co;
    sincosf((float)ang, &s, &co);
    float Lre = modL * co, Lim = modL * s;
    float pr = 0.f, pi = 0.f;
    for (int c = 0; c < NCHUNK; ++c) {
        size_t idx = (size_t)(b * NCHUNK + c) * 512 + n;
        prefix[idx] = make_float2(pr, pi);
        float2 ev = carry[idx];
        float nr = fmaf(Lre, pr, fmaf(-Lim, pi, ev.x));
        float ni = fmaf(Lre, pi, fmaf(Lim, pr, ev.y));
        pr = nr; pi = ni;
    }
}

__global__ void scan_apply(const unsigned* __restrict__ Bu, const float* __restrict__ nu_log,
                           const float* __restrict__ theta_log, const float2* __restrict__ prefix,
                           char* __restrict__ Apack) {
    int q = blockIdx.x * 256 + threadIdx.x;
    int n = q & 511, c = (q >> 9) & 63, b = q >> 15;
    float mod = expf(-expf(nu_log[n]));
    float th = expf(theta_log[n]);
    float s, co;
    sincosf(th, &s, &co);
    float Lre = mod * co, Lim = mod * s;
    const unsigned* p = Bu + ((size_t)(b * TDIM + c * CHUNK)) * 512 + n;
    float2 pv = prefix[(size_t)(b * NCHUNK + c) * 512 + n];
    float xr = pv.x, xi = pv.y;
    int kp = (2 * n) & 63;
    int kk = kp >> 5, km = kp & 31;
    int half = km >> 4, gg = (km & 15) >> 2, j = km & 3;
    int cc = (kk << 2) | gg;
    int partial = (n >> 5) * 128 + half * 8 + j * 2;
    int row0 = b * TDIM + c * CHUNK;
#pragma unroll 8
    for (int t = 0; t < CHUNK; ++t) {
        unsigned wv = p[(size_t)t * 512];
        float nr = fmaf(Lre, xr, fmaf(-Lim, xi, bflo(wv)));
        float ni = fmaf(Lre, xi, fmaf(Lim, xr, bfhi(wv)));
        xr = nr; xi = ni;
        int row = row0 + t;
        size_t off = (size_t)row * 3072 + ((cc ^ (row & 7)) << 4) + partial;
        *reinterpret_cast<unsigned*>(Apack + off) =
            (unsigned)f2bf(xr) | ((unsigned)f2bf(xi) << 16);
    }
}

extern "C" void kernel_launch(void* const* d_in, const int* in_sizes, int n_in,
                              void* d_out, int out_size, void* d_ws, size_t ws_size,
                              hipStream_t stream) {
    const float* u         = (const float*)d_in[0];
    const float* nu_log    = (const float*)d_in[1];
    const float* theta_log = (const float*)d_in[2];
    const float* gamma_log = (const float*)d_in[3];
    const float* B_re      = (const float*)d_in[4];
    const float* B_im      = (const float*)d_in[5];
    const float* C_re      = (const float*)d_in[6];
    const float* C_im      = (const float*)d_in[7];
    const float* D         = (const float*)d_in[8];

    char* ws = (char*)d_ws;
    char* Apack = ws;                                   // 65536*3072 B = 201 MB (perm layout)
    size_t off = (size_t)MTOT * 3072;
    char* W1 = ws + off; off += 1024 * 1024;            // 1 MB
    char* W2 = ws + off; off += 512 * 3072;             // 1.5 MB
    float2* carry  = (float2*)(ws + off); off += (size_t)BDIM * NCHUNK * 512 * 8;
    float2* prefix = (float2*)(ws + off); off += (size_t)BDIM * NCHUNK * 512 * 8;

    unsigned short* Bu = (unsigned short*)d_out;  // 65536*1024 ushort == out bytes

    prep_w1<<<dim3(2, 1024), 256, 0, stream>>>(B_re, B_im, gamma_log, W1);
    prep_w2<<<dim3(6, 512), 256, 0, stream>>>(C_re, C_im, D, W2);
    convert_u<<<32768, 256, 0, stream>>>((const float4*)u, Apack);
    // GEMM1: Bu = u_bf16 . W1^T  (M=65536, N=1024, K=512) + fused chunk-carry
    gemm_nt<1, 4><<<1024, 512, 0, stream>>>(Apack + 16 * 128, 3072, W1, 1024,
                                            (void*)Bu, 8, carry, nu_log, theta_log);
    scan_prefix<<<32, 256, 0, stream>>>(carry, nu_log, theta_log, prefix);
    scan_apply<<<2048, 256, 0, stream>>>((const unsigned*)Bu, nu_log, theta_log, prefix, Apack);
    // GEMM2: y = Apack . W2^T  (M=65536, N=512, K=1536), f32 out
    gemm_nt<0, 2><<<512, 512, 0, stream>>>(Apack, 3072, W2, 3072, d_out, 24,
                                           nullptr, nullptr, nullptr);
}